// Round 13
// baseline (21365.128 us; speedup 1.0000x reference)
//
#include <hip/hip_runtime.h>

#define B_ 4096
#define L_ 15
#define NSTEP_ 5
#define VOC_ 30005
#define PAD_ 30003

typedef _Float16 f16;
typedef f16  f16x8 __attribute__((ext_vector_type(8)));
typedef float f32x16 __attribute__((ext_vector_type(16)));

__device__ __forceinline__ float sigf(float x){ return 1.0f/(1.0f+expf(-x)); }

#define MFMA_(d,a,b) d = __builtin_amdgcn_mfma_f32_32x32x16_f16(a,b,d,0,0,0)

__device__ __forceinline__ void gll16(const f16* g, f16* l){
  __builtin_amdgcn_global_load_lds(
      (const __attribute__((address_space(1))) void*)g,
      (__attribute__((address_space(3))) void*)l, 16, 0, 0);
}

// ---------------------------------------------------------------- params
struct RecParams {
  const f16 *A1h_0,*A1l_0,*A1h_1,*A1l_1;   // x-part arrays (layer1 path)
  const f16 *A2h_0,*A2l_0,*A2h_1,*A2l_1;   // h-part arrays
  const f16 *Wfh_0,*Wfl_0,*Wfh_1,*Wfl_1;   // fragment-order W
  const float *bias_0,*bias_1;
  const f16 *embH,*embL,*flagpg;           // split emb tables + flag page
  const int *st,*ids;
  float *c_0,*c_1,*h2_0,*h2_1;
  f16 *hh_0,*hl_0,*hh_1,*hl_1;
  int lda1, lda2, ldh, ldh2, k1p, k2p, first, gather, t_0, t_1, pos, b0c, act0, act1;
};

// swizzled byte offset into a [128 rows][16 k] f16 (4KB) LDS sub-array (Gray).
__device__ __forceinline__ int swz(int row, int s){
  int u = ((row&7)<<1) | s;
  return ((row>>3)<<8) + ((u ^ (u>>1))<<4);
}

// --------------------------------- fused split-f16 MFMA GEMM + LSTM cell
// 128x128 tile, 4 waves. BK=32 tiles. A(h,l) staged via global_load_lds into
// TRIPLE-buffered swizzled LDS (issued 2 tiles ahead; source pre-swizzled per
// Gray decode -> LDS content matches swz()). B from global into regs,
// prefetched AFTER the MFMA cluster so it stays in flight ACROSS the barrier.
// Barrier = counted s_waitcnt vmcnt(8) + raw s_barrier (never a full drain):
// per tile each wave issues exactly 4 glls + 8 B-loads; at the barrier the 8
// newest ops are the B-prefetch, so vmcnt(8) exactly drains next tile's glls.
__global__ __launch_bounds__(256,2) void rec_gemm(RecParams p){
  const int id  = blockIdx.x;
  const int ct4 = id & 15;           // 128-col group
  const int dir = (id >> 4) & 1;     // 0 = fw, 1 = bw
  if (!(dir ? p.act1 : p.act0)) return;
  const f16* A1h = dir ? p.A1h_1 : p.A1h_0;
  const f16* A1l = dir ? p.A1l_1 : p.A1l_0;
  const f16* A2h = dir ? p.A2h_1 : p.A2h_0;
  const f16* A2l = dir ? p.A2l_1 : p.A2l_0;
  const f16* Wfh = dir ? p.Wfh_1 : p.Wfh_0;
  const f16* Wfl = dir ? p.Wfl_1 : p.Wfl_0;
  const float* bias = dir ? p.bias_1 : p.bias_0;
  float* cbuf = dir ? p.c_1 : p.c_0;
  float* h2   = dir ? p.h2_1 : p.h2_0;
  f16* hhb = dir ? p.hh_1 : p.hh_0;
  f16* hlb = dir ? p.hl_1 : p.hl_0;
  const int tcur = dir ? p.t_1 : p.t_0;

  const int tid  = threadIdx.x;
  const int lane = tid & 63;
  const int w    = tid >> 6;         // 0..3
  const int mbase = (id >> 5) * 128;

  __shared__ union {
    float z[128*128];                // 64 KB epilogue
    f16   stg[3][4][2048];           // [buf][Ah_k0,Al_k0,Ah_k1,Al_k1] 4KB each
  } sm;

  f32x16 accM[2][2], accX[2][2];
#pragma unroll
  for (int i=0;i<2;i++)
#pragma unroll
    for (int j=0;j<2;j++)
#pragma unroll
      for (int r=0;r<16;r++){ accM[i][j][r]=0.f; accX[i][j][r]=0.f; }

  // a-frag read offsets (validated scheme, per 4KB sub-array)
  const int arow = (w&1)*64 + (lane&31);
  const int fs = lane>>5;
  const int aoff0 = swz(arow,    fs), aoff1 = swz(arow+32, fs);

  // b-frag global fragment pointers: wave covers 2 ct units (64 cols)
  const int ct0 = ct4*4 + (w>>1)*2;
  const f16* WfhL = Wfh + (size_t)lane*8;
  const f16* WflL = Wfl + (size_t)lane*8;

  // gll staging: wave w fills sub-array w = {ksub=w>>1, part=(w&1)?lo:hi}.
  // gll q writes LDS units q*64+lane (linear); source (row,s) = Gray-decode
  // of the unit within its 8-row group -> LDS content matches swz().
  const int ksubW = w >> 1;
  const f16* srcEmb = (w&1) ? p.embL : p.embH;
  const f16* srcA1  = (w&1) ? A1l : A1h;
  const f16* srcA2  = (w&1) ? A2l : A2h;
  int rowQ[4], sQ[4], tokT[4], tokI[4];
#pragma unroll
  for (int q=0;q<4;q++){
    int uu = q*64 + lane;
    int d = uu & 15; d ^= d>>1; d ^= d>>2;
    rowQ[q] = ((uu>>4)<<3) + (d>>1);
    sQ[q]   = d & 1;
    tokT[q] = 0; tokI[q] = 0;
  }
  int zflag = 0;
  if (p.gather){
    zflag = (tcur == p.pos) ? 1 : 0;
#pragma unroll
    for (int q=0;q<4;q++){
      int gb = p.b0c + mbase + rowQ[q];
      tokT[q] = p.st [gb*L_ + tcur];
      tokI[q] = p.ids[gb*L_ + tcur];
    }
  }
  const f16* ones0 = p.flagpg;       // {1,0,0,0,0,0,0,0}
  const f16* zeros = p.flagpg + 8;   // 16B zeros
  const int ktot = p.k1p + p.k2p;

  auto stage = [&](int t, int buf){
    f16* dst = &sm.stg[buf][w][0];
#pragma unroll
    for (int q=0;q<4;q++){
      int koff = ksubW*16 + sQ[q]*8;
      const f16* src;
      if (t < p.k1p){
        if (p.gather){
          if (t < 8)       src = zflag ? zeros
                               : (srcEmb + (size_t)tokT[q]*256 + t*32 + koff);
          else if (t < 16) src = srcEmb + (size_t)tokI[q]*256 + (t-8)*32 + koff;
          else             src = (zflag && w==0 && sQ[q]==0) ? ones0 : zeros;
        } else {
          src = srcA1 + (size_t)(mbase+rowQ[q])*p.lda1 + t*32 + koff;
        }
      } else {
        src = srcA2 + (size_t)(mbase+rowQ[q])*p.lda2 + (t - p.k1p)*32 + koff;
      }
      gll16(src, dst + q*512);
    }
  };
  auto loadB = [&](int t, f16x8* rb){
    size_t b0 = ((size_t)(2*t+0)*64 + ct0)*512;
    size_t b1 = ((size_t)(2*t+1)*64 + ct0)*512;
    rb[0] = *(const f16x8*)(WfhL + b0);
    rb[1] = *(const f16x8*)(WfhL + b0 + 512);
    rb[2] = *(const f16x8*)(WflL + b0);
    rb[3] = *(const f16x8*)(WflL + b0 + 512);
    rb[4] = *(const f16x8*)(WfhL + b1);
    rb[5] = *(const f16x8*)(WfhL + b1 + 512);
    rb[6] = *(const f16x8*)(WflL + b1);
    rb[7] = *(const f16x8*)(WflL + b1 + 512);
  };

  f16x8 rb[8];
  stage(0,0); stage(1,1); loadB(0, rb);
  asm volatile("s_waitcnt vmcnt(12)" ::: "memory");   // drain stage(0) only
  __builtin_amdgcn_s_barrier();
  __builtin_amdgcn_sched_barrier(0);

  for (int t=0; t<ktot; ++t){
    const int cur = t % 3;
    const char* s0h = (const char*)sm.stg[cur][0];
    const char* s0l = (const char*)sm.stg[cur][1];
    const char* s1h = (const char*)sm.stg[cur][2];
    const char* s1l = (const char*)sm.stg[cur][3];
    f16x8 a00h = *(const f16x8*)(s0h + aoff0);
    f16x8 a01h = *(const f16x8*)(s0h + aoff1);
    f16x8 a00l = *(const f16x8*)(s0l + aoff0);
    f16x8 a01l = *(const f16x8*)(s0l + aoff1);
    f16x8 a10h = *(const f16x8*)(s1h + aoff0);
    f16x8 a11h = *(const f16x8*)(s1h + aoff1);
    f16x8 a10l = *(const f16x8*)(s1l + aoff0);
    f16x8 a11l = *(const f16x8*)(s1l + aoff1);
    if (t+2 < ktot) stage(t+2, (t+2)%3);   // A two tiles ahead (in flight)
    __builtin_amdgcn_s_setprio(1);
    // ksub0 (distinct-acc grouping)
    MFMA_(accM[0][0], a00h, rb[0]); MFMA_(accM[1][0], a01h, rb[0]);
    MFMA_(accM[0][1], a00h, rb[1]); MFMA_(accM[1][1], a01h, rb[1]);
    MFMA_(accX[0][0], a00h, rb[2]); MFMA_(accX[1][0], a01h, rb[2]);
    MFMA_(accX[0][1], a00h, rb[3]); MFMA_(accX[1][1], a01h, rb[3]);
    MFMA_(accX[0][0], a00l, rb[0]); MFMA_(accX[1][0], a01l, rb[0]);
    MFMA_(accX[0][1], a00l, rb[1]); MFMA_(accX[1][1], a01l, rb[1]);
    // ksub1
    MFMA_(accM[0][0], a10h, rb[4]); MFMA_(accM[1][0], a11h, rb[4]);
    MFMA_(accM[0][1], a10h, rb[5]); MFMA_(accM[1][1], a11h, rb[5]);
    MFMA_(accX[0][0], a10h, rb[6]); MFMA_(accX[1][0], a11h, rb[6]);
    MFMA_(accX[0][1], a10h, rb[7]); MFMA_(accX[1][1], a11h, rb[7]);
    MFMA_(accX[0][0], a10l, rb[4]); MFMA_(accX[1][0], a11l, rb[4]);
    MFMA_(accX[0][1], a10l, rb[5]); MFMA_(accX[1][1], a11l, rb[5]);
    __builtin_amdgcn_s_setprio(0);
    if (t+1 < ktot){
      loadB(t+1, rb);                      // crosses the barrier
      asm volatile("s_waitcnt vmcnt(8)" ::: "memory");  // drain stage(t+1)
      __builtin_amdgcn_s_barrier();
      __builtin_amdgcn_sched_barrier(0);
    }
  }

  __syncthreads();   // full drain once before reusing union as z

  // ---- epilogue: z tiles -> LDS (regroup gates), then fused LSTM cell
#pragma unroll
  for (int tm=0;tm<2;tm++)
#pragma unroll
   for (int tn=0;tn<2;tn++){
    int lcol = (w>>1)*64 + tn*32 + (lane&31);
    float bv = bias[ct4*128 + lcol];
#pragma unroll
    for (int r=0;r<16;r++){
      int lrow = (w&1)*64 + tm*32 + (r&3) + 8*(r>>2) + 4*(lane>>5);
      sm.z[lrow*128 + lcol] = accM[tm][tn][r] + 0.000244140625f*accX[tm][tn][r] + bv;
    }
   }
  __syncthreads();

  const int nb = ct4*32;   // hidden-unit base for this block
#pragma unroll
  for (int it=0; it<16; ++it){
    int idx = it*256 + tid;
    int nq = idx & 31, row = idx >> 5;
    float4 g4 = *(const float4*)&sm.z[row*128 + nq*4];
    int m = mbase + row, n = nb + nq;
    float cp = p.first ? 0.f : cbuf[(size_t)m*512 + n];
    float cc = sigf(g4.y)*cp + sigf(g4.x)*tanhf(g4.z);
    float hv = sigf(g4.w)*tanhf(cc);
    cbuf[(size_t)m*512 + n] = cc;
    f16 hi = (f16)hv;
    f16 lo = (f16)((hv - (float)hi)*4096.0f);
    hhb[(size_t)m*p.ldh + n] = hi;
    hlb[(size_t)m*p.ldh + n] = lo;
    if (h2) h2[(size_t)m*p.ldh2 + n] = hv;
  }
}

// ------------------------------------------- prep: W in MFMA fragment order
__global__ void prep_w0(const float* Wih, const float* Whh, const float* b0,
                        f16* Wfh, f16* Wfl, float* bp){
  int gid = blockIdx.x*blockDim.x + threadIdx.x;
  const int PER_DIR = 66*64*64*8;
  if (gid >= 2*PER_DIR) return;
  int dir = gid / PER_DIR;
  int rem = gid % PER_DIR;
  int j = rem & 7, lane = (rem>>3)&63, ct = (rem>>9)&63, kt16 = rem>>15;
  int n4g = ct*32 + (lane&31);
  int n = n4g>>2, g = n4g&3;
  int srow = dir*2048 + g*512 + n;
  int k = kt16*16 + ((lane>>5)<<3) + j;     // padded K: [Wih 513 | pad 31 | Whh 512]
  float v;
  if (k < 513)       v = Wih[(size_t)srow*513 + k];
  else if (k < 544)  v = 0.f;
  else               v = Whh[(size_t)srow*512 + (k-544)];
  f16 hi = (f16)v;
  Wfh[gid] = hi;
  Wfl[gid] = (f16)((v - (float)hi)*4096.0f);
  if (kt16==0 && (lane>>5)==0 && j==0) bp[dir*2048 + n4g] = b0[srow];
}

__global__ void prep_w1(const float* Wih, const float* Whh, const float* b1,
                        f16* Wfh, f16* Wfl, float* bp){
  int gid = blockIdx.x*blockDim.x + threadIdx.x;
  const int PER_DIR = 96*64*64*8;
  if (gid >= 2*PER_DIR) return;
  int dir = gid / PER_DIR;
  int rem = gid % PER_DIR;
  int j = rem & 7, lane = (rem>>3)&63, ct = (rem>>9)&63, kt16 = rem>>15;
  int n4g = ct*32 + (lane&31);
  int n = n4g>>2, g = n4g&3;
  int srow = dir*2048 + g*512 + n;
  int k = kt16*16 + ((lane>>5)<<3) + j;     // [Wih 1024 | Whh 512]
  float v;
  if (k < 1024) v = Wih[(size_t)srow*1024 + k];
  else          v = Whh[(size_t)srow*512 + (k-1024)];
  f16 hi = (f16)v;
  Wfh[gid] = hi;
  Wfl[gid] = (f16)((v - (float)hi)*4096.0f);
  if (kt16==0 && (lane>>5)==0 && j==0) bp[dir*2048 + n4g] = b1[srow];
}

__global__ void prep_emb(const float* emb, f16* eh, f16* el){
  int gid = blockIdx.x*blockDim.x + threadIdx.x;
  if (gid >= VOC_*256) return;
  float v = emb[gid];
  f16 hi = (f16)v;
  eh[gid] = hi;
  el[gid] = (f16)((v - (float)hi)*4096.0f);
}

__global__ void prep_mlpwt(const float* mW, float* wt){
  int gid = blockIdx.x*blockDim.x + threadIdx.x;
  if (gid >= 100*1040) return;
  int j = gid / 1040, k = gid % 1040;
  wt[k*100 + j] = mW[gid];
}

__global__ __launch_bounds__(128) void prep_encproj(const float* enc, const float* delv,
                        const float* holdv, const float* m1W, const float* m1b, float* ep){
  int r = blockIdx.x;
  __shared__ float row[256];
  const float* src = (r < VOC_) ? enc + (size_t)r*256 : (r == VOC_ ? delv : holdv);
  for (int i=threadIdx.x;i<256;i+=128) row[i]=src[i];
  __syncthreads();
  int j = threadIdx.x;
  if (j < 100){
    double s = (double)m1b[j];
    const float* wr = m1W + (size_t)j*298;
    for (int k=0;k<256;k++) s += (double)wr[k] * (double)row[k];
    ep[(size_t)r*100 + j] = (float)s;
  }
}

__global__ void init_st(const int* ids, const int* seqlen, int* st, int* len, f16* flagpg){
  int gid = blockIdx.x*blockDim.x + threadIdx.x;
  if (gid < B_*L_) st[gid] = ids[gid];
  if (gid < B_)    len[gid] = seqlen[gid];
  if (gid < 16)    flagpg[gid] = (gid==0) ? (f16)1.0f : (f16)0.0f;
}

__global__ void sentinel(float* out, float v){
  int gid = blockIdx.x*blockDim.x + threadIdx.x;
  if (gid < B_*NSTEP_) out[gid] = v;
}

// ------------------------------------------------- scoring + sequence edit
__global__ __launch_bounds__(128) void score_update(
    const float* pooled, const float* keypos, const float* mWt, const float* mb,
    const float* ep, const float* m1W, const int* repw, const int* valid,
    int* st, int* len, float* outPis, float* outActs, int step, int pos, int b0){
  int b = blockIdx.x;
  int bg = b0 + b;
  __shared__ float rep[1040];
  __shared__ float r100[100];
  __shared__ double sc[42];
  int tid = threadIdx.x;
  for (int i=tid;i<1024;i+=128) rep[i] = pooled[(size_t)b*1024+i];
  if (tid < 16){
    if (tid == 0) rep[1024] = keypos[bg*L_+pos];
    else          rep[1024+tid] = ((tid-1)==pos) ? 1.f : 0.f;
  }
  __syncthreads();
  if (tid < 100){
    double s = (double)mb[tid];
    for (int k=0;k<1040;k++) s += (double)mWt[k*100+tid] * (double)rep[k];
    r100[tid] = (float)s;
  }
  __syncthreads();
  if (tid < 42){
    int row = (tid < 40) ? repw[((size_t)bg*NSTEP_+step)*40 + tid] : (VOC_ + (tid-40));
    const float* er = ep + (size_t)row*100;
    double s = 0.0;
    for (int j=0;j<100;j++) s += (double)er[j] * (double)r100[j];
    for (int j=0;j<100;j++) s += (double)m1W[j*298 + 256 + tid] * (double)r100[j];
    sc[tid] = s;
  }
  __syncthreads();
  if (tid == 0){
    double mx = sc[0]; int am = 0;
    for (int k=1;k<42;k++) if (sc[k] > mx){ mx = sc[k]; am = k; }
    double sum = 0.0;
    for (int k=0;k<42;k++) sum += exp(sc[k]-mx);
    float pi = (float)(1.0/sum);
    int vid = valid[bg*NSTEP_+step];
    int ln  = len[bg];
    int repb = (am < 20) ? 1 : 0;
    int insb = (am >= 20 && am < 40) ? 1 : 0;
    int delb = (am == 40) ? 1 : 0;
    int repf = repb*vid;
    int insf = insb*vid*(((ln+insb) <= 15) ? 1 : 0);
    int delf = delb*vid*(((ln-delb) >  2) ? 1 : 0);
    int T = L_ - pos;
    int tail[13];
    for (int j=0;j<T;j++) tail[j] = st[bg*L_+pos+j];
    int aw = repw[((size_t)bg*NSTEP_+step)*40 + (am < 20 ? am : 19)];
    for (int j=0;j<T;j++){
      int rv = (j==0) ? aw : tail[j];
      int iv = (j==0) ? aw : tail[j-1];
      int dv = (j < T-1) ? tail[j+1] : PAD_;
      int hv = tail[j];
      int nv = repf ? rv : (insf ? iv : (delf ? dv : hv));
      st[bg*L_+pos+j] = nv;
    }
    len[bg] = ln + insf - delf;
    outPis[bg*NSTEP_+step]  = pi;
    outActs[bg*NSTEP_+step] = (float)am;
  }
}

__global__ void finalize(const int* st, const int* len, float* out){
  int gid = blockIdx.x*blockDim.x + threadIdx.x;
  if (gid < B_*L_)            out[2*B_*NSTEP_ + gid] = (float)st[gid];
  else if (gid < B_*L_ + B_)  out[2*B_*NSTEP_ + B_*L_ + (gid - B_*L_)] = (float)len[gid - B_*L_];
}

// ---------------------------------------------------------------- launch
extern "C" void kernel_launch(void* const* d_in, const int* in_sizes, int n_in,
                              void* d_out, int out_size, void* d_ws, size_t ws_size,
                              hipStream_t stream) {
  const int*   ids    = (const int*)  d_in[0];
  const float* keypos = (const float*)d_in[1];
  const int*   seqlen = (const int*)  d_in[2];
  const int*   repw   = (const int*)  d_in[3];
  const int*   valid  = (const int*)  d_in[4];
  const float* emb    = (const float*)d_in[5];
  const float* enc    = (const float*)d_in[6];
  const float* Wih0   = (const float*)d_in[7];
  const float* Whh0   = (const float*)d_in[8];
  const float* b0     = (const float*)d_in[9];
  const float* Wih1   = (const float*)d_in[10];
  const float* Whh1   = (const float*)d_in[11];
  const float* b1     = (const float*)d_in[12];
  const float* delv   = (const float*)d_in[13];
  const float* holdv  = (const float*)d_in[14];
  const float* mW     = (const float*)d_in[15];
  const float* mb     = (const float*)d_in[16];
  const float* m1W    = (const float*)d_in[17];
  const float* m1b    = (const float*)d_in[18];
  float* out = (float*)d_out;

  const size_t W0PD = (size_t)66*64*64*8;   // f16 per dir (K padded to 1056)
  const size_t W1PD = (size_t)96*64*64*8;

  char* ws = (char*)d_ws;
  size_t off = 0;
  auto allocB = [&](size_t bytes) -> char* {
    char* pp = ws + off; off += (bytes + 255) & ~size_t(255); return pp;
  };
  f16*  Wf0h = (f16*)allocB(2*W0PD*2);
  f16*  Wf0l = (f16*)allocB(2*W0PD*2);
  f16*  Wf1h = (f16*)allocB(2*W1PD*2);
  f16*  Wf1l = (f16*)allocB(2*W1PD*2);
  float* bp0 = (float*)allocB(4096*4);
  float* bp1 = (float*)allocB(4096*4);
  f16*  embH = (f16*)allocB((size_t)VOC_*256*2);
  f16*  embL = (f16*)allocB((size_t)VOC_*256*2);
  float* mWt = (float*)allocB(104000*4);
  float* ep  = (float*)allocB((size_t)30007*100*4);
  int* stbuf  = (int*)allocB(B_*L_*4);
  int* lenbuf = (int*)allocB(B_*4);
  f16* flagpg = (f16*)allocB(256);
  size_t fixedB = off;

  const int cands[6] = {4096, 2048, 1024, 512, 256, 128};
  int Bc = 0;
  for (int ci=0; ci<6; ++ci){
    size_t c = cands[ci];
    size_t chunkB = c*(size_t)(15*1024*2*2 + 4*512*2*2 + 2*512*4 + 2*512*4 + 1024*4) + 8*256;
    if (fixedB + chunkB <= ws_size){ Bc = (int)c; break; }
  }
  if (!Bc){
    float code = 100000.0f + (float)(ws_size >> 20);
    sentinel<<<(B_*NSTEP_+255)/256,256,0,stream>>>(out, code);
    return;
  }
  f16* o0h = (f16*)allocB((size_t)L_*Bc*1024*2);
  f16* o0l = (f16*)allocB((size_t)L_*Bc*1024*2);
  f16* h1h = (f16*)allocB((size_t)4*Bc*512*2);
  f16* h1l = (f16*)allocB((size_t)4*Bc*512*2);
  float* c0 = (float*)allocB((size_t)2*Bc*512*4);
  float* c1 = (float*)allocB((size_t)2*Bc*512*4);
  float* pooled = (float*)allocB((size_t)Bc*1024*4);

  prep_w0<<<(int)((2*W0PD+255)/256),256,0,stream>>>(Wih0, Whh0, b0, Wf0h, Wf0l, bp0);
  prep_w1<<<(int)((2*W1PD+255)/256),256,0,stream>>>(Wih1, Whh1, b1, Wf1h, Wf1l, bp1);
  prep_emb<<<(VOC_*256+255)/256,256,0,stream>>>(emb, embH, embL);
  prep_mlpwt<<<(100*1040+255)/256,256,0,stream>>>(mW, mWt);
  prep_encproj<<<30007,128,0,stream>>>(enc, delv, holdv, m1W, m1b, ep);
  init_st<<<(B_*L_+255)/256,256,0,stream>>>(ids, seqlen, stbuf, lenbuf, flagpg);

  const int nblk = (Bc/128) * 32;

  for (int b0c=0; b0c<B_; b0c+=Bc){
    for (int step=0; step<NSTEP_; ++step){
      int pos = step + 2;   // i % 12 + 2 for i=0..4

      // ---- layer 0: full 15 timesteps, fw (t=ts) + bw (t=14-ts)
      for (int ts=0; ts<L_; ++ts){
        int tf = ts, tb = 14-ts;
        RecParams p{};
        p.gather = 1; p.t_0 = tf; p.t_1 = tb; p.pos = pos; p.b0c = b0c;
        p.embH = embH; p.embL = embL; p.flagpg = flagpg; p.st = stbuf; p.ids = ids;
        p.k1p = 17; p.k2p = ts ? 16 : 0;
        size_t of0 = (size_t)(ts?tf-1:0)*Bc*1024;
        size_t of1 = (size_t)(ts?tb+1:0)*Bc*1024 + (ts?512:0);
        p.A2h_0 = o0h + of0;  p.A2l_0 = o0l + of0;
        p.A2h_1 = o0h + of1;  p.A2l_1 = o0l + of1;
        p.lda2 = 1024;
        p.Wfh_0 = Wf0h;        p.Wfl_0 = Wf0l;
        p.Wfh_1 = Wf0h + W0PD; p.Wfl_1 = Wf0l + W0PD;
        p.bias_0 = bp0; p.bias_1 = bp0 + 2048;
        p.c_0 = c0; p.c_1 = c0 + (size_t)Bc*512;
        p.hh_0 = o0h + (size_t)tf*Bc*1024;       p.hl_0 = o0l + (size_t)tf*Bc*1024;
        p.hh_1 = o0h + (size_t)tb*Bc*1024 + 512; p.hl_1 = o0l + (size_t)tb*Bc*1024 + 512;
        p.ldh = 1024;
        p.h2_0 = nullptr; p.h2_1 = nullptr; p.ldh2 = 1024;
        p.first = (ts==0); p.act0 = 1; p.act1 = 1;
        rec_gemm<<<dim3(nblk),256,0,stream>>>(p);
      }

      // ---- layer 1: fw needs t<=pos only, bw needs t>=pos only
      int nL1 = L_ - pos;
      for (int ts=0; ts<nL1; ++ts){
        RecParams p{};
        int tf = ts, tb = 14-ts;
        int parR = (ts-1)&1, parW = ts&1;
        p.gather = 0; p.flagpg = flagpg;
        p.A1h_0 = o0h + (size_t)tf*Bc*1024;  p.A1l_0 = o0l + (size_t)tf*Bc*1024;
        p.A1h_1 = o0h + (size_t)tb*Bc*1024;  p.A1l_1 = o0l + (size_t)tb*Bc*1024;
        p.lda1 = 1024; p.k1p = 32;
        p.k2p  = ts ? 16 : 0;
        size_t r0 = (size_t)(0*2 + (ts?parR:0))*Bc*512;
        size_t r1 = (size_t)(1*2 + (ts?parR:0))*Bc*512;
        p.A2h_0 = h1h + r0; p.A2l_0 = h1l + r0;
        p.A2h_1 = h1h + r1; p.A2l_1 = h1l + r1;
        p.lda2 = 512;
        p.Wfh_0 = Wf1h;        p.Wfl_0 = Wf1l;
        p.Wfh_1 = Wf1h + W1PD; p.Wfl_1 = Wf1l + W1PD;
        p.bias_0 = bp1; p.bias_1 = bp1 + 2048;
        p.c_0 = c1; p.c_1 = c1 + (size_t)Bc*512;
        size_t w0 = (size_t)(0*2 + parW)*Bc*512;
        size_t w1 = (size_t)(1*2 + parW)*Bc*512;
        p.hh_0 = h1h + w0; p.hl_0 = h1l + w0;
        p.hh_1 = h1h + w1; p.hl_1 = h1l + w1;
        p.ldh = 512;
        p.h2_0 = (ts == pos)    ? pooled        : nullptr;
        p.h2_1 = (ts == 14-pos) ? (pooled+512)  : nullptr;
        p.ldh2 = 1024;
        p.first = (ts==0);
        p.act0 = (ts <= pos) ? 1 : 0; p.act1 = 1;
        rec_gemm<<<dim3(nblk),256,0,stream>>>(p);
      }

      score_update<<<Bc,128,0,stream>>>(pooled, keypos, mWt, mb, ep, m1W, repw, valid,
                                        stbuf, lenbuf, out, out + B_*NSTEP_, step, pos, b0c);
    }
  }
  finalize<<<(B_*L_+B_+255)/256,256,0,stream>>>(stbuf, lenbuf, out);
}